// Round 1
// baseline (47.051 us; speedup 1.0000x reference)
//
#include <hip/hip_runtime.h>

#define NB 256
#define NP 512
#define NE 256
#define NH 128
#define PT 64              // pool-dim rows per tile
#define NT (NP / PT)       // 8 tiles
#define RS 264             // LDS row stride in shorts (256 + 8 pad -> even bank spread)

typedef __attribute__((ext_vector_type(8))) short bf16x8;
typedef __attribute__((ext_vector_type(4))) short short4v;
typedef __attribute__((ext_vector_type(4))) float f32x4;

__device__ __forceinline__ short f2bf(float f) {
  union { float f; unsigned u; } v; v.f = f;
  unsigned r = v.u + 0x7fffu + ((v.u >> 16) & 1u);   // round-to-nearest-even
  return (short)(r >> 16);
}
__device__ __forceinline__ float bf2f(short s) {
  union { unsigned u; float f; } v;
  v.u = ((unsigned)(unsigned short)s) << 16;
  return v.f;
}
// tanh(x) = 1 - 2/(exp2(2*log2e*x)+1); exact at +-inf, ~1e-7 rel error
__device__ __forceinline__ float fast_tanh(float x) {
  float u = __builtin_amdgcn_exp2f(x * 2.8853900817779268f);
  return 1.0f - 2.0f * __builtin_amdgcn_rcpf(u + 1.0f);
}

__global__ __launch_bounds__(512, 2) void pathattn_kernel(
    const float* __restrict__ x, const float* __restrict__ w1,
    const float* __restrict__ w2, float* __restrict__ out) {
  __shared__ short xs[2][PT * RS];     // bf16 x tiles, double-buffered (~66 KB)
  __shared__ float sp[2][PT];          // per-column-group score partials
  __shared__ float expw[PT];           // exp(score) for current tile
  __shared__ float pool2[2][NE];       // pooled partials (2 p-halves)
  __shared__ float zarr[PT];           // Z partials

  const int tid  = threadIdx.x;
  const int lane = tid & 63;
  const int wid  = tid >> 6;           // 0..7
  const int jg   = wid & 1;            // column group: cols jg*64 .. +64
  const int h    = wid >> 1;           // row subtile: rows h*16 .. +16
  const int b    = blockIdx.x;
  const float* xb = x + (size_t)b * NP * NE;

  // ---- hoist w1 into registers as bf16 B-fragments (4 j-tiles x 8 k-tiles) ----
  // B[k][n] = w1[j0+n][k]; frag: lane holds n=lane&15, k = kt*32 + (lane>>4)*8 + i
  bf16x8 bfrag[4][8];
  float w2v[4];
  {
    const int n  = lane & 15;
    const int kg = lane >> 4;
    #pragma unroll
    for (int jt = 0; jt < 4; ++jt) {
      const int j = jg * 64 + jt * 16 + n;
      w2v[jt] = w2[j];
      #pragma unroll
      for (int kt = 0; kt < 8; ++kt) {
        const f32x4* s = (const f32x4*)(w1 + j * NE + kt * 32 + kg * 8);
        f32x4 a = s[0], c = s[1];
        bf16x8 v;
        v[0]=f2bf(a[0]); v[1]=f2bf(a[1]); v[2]=f2bf(a[2]); v[3]=f2bf(a[3]);
        v[4]=f2bf(c[0]); v[5]=f2bf(c[1]); v[6]=f2bf(c[2]); v[7]=f2bf(c[3]);
        bfrag[jt][kt] = v;
      }
    }
  }

  // ---- staging helpers: global fp32 -> regs -> bf16 LDS (padded rows) ----
  f32x4 streg[8];
  auto issue_loads = [&](int tile) {
    const float* base = xb + tile * PT * NE;
    #pragma unroll
    for (int rr = 0; rr < 8; ++rr) {
      int f   = rr * 512 + tid;        // float4 index within tile
      int row = f >> 6;                // 64 float4 per row
      int c4  = f & 63;
      streg[rr] = *(const f32x4*)(base + row * NE + c4 * 4);
    }
  };
  auto write_tile = [&](int buf) {
    #pragma unroll
    for (int rr = 0; rr < 8; ++rr) {
      int f   = rr * 512 + tid;
      int row = f >> 6;
      int c4  = f & 63;
      short4v v;
      v[0]=f2bf(streg[rr][0]); v[1]=f2bf(streg[rr][1]);
      v[2]=f2bf(streg[rr][2]); v[3]=f2bf(streg[rr][3]);
      *(short4v*)(&xs[buf][row * RS + c4 * 4]) = v;
    }
  };

  issue_loads(0);
  write_tile(0);
  __syncthreads();

  float pacc = 0.f;                    // pooling accumulator (one e per thread)
  float zacc = 0.f;                    // Z accumulator (threads < PT)
  const int pe = tid & 255;
  const int pq = tid >> 8;             // 0..1: which 32-row half of the tile

  for (int t = 0; t < NT; ++t) {
    const int cur = t & 1;
    if (t + 1 < NT) issue_loads(t + 1);   // async; drains by first barrier

    // ---- MFMA score phase: h_pre = x_tile @ w1^T, then tanh*w2, reduce ----
    f32x4 acc[4];
    #pragma unroll
    for (int jt = 0; jt < 4; ++jt) acc[jt] = (f32x4){0.f,0.f,0.f,0.f};
    const int arow = h * 16 + (lane & 15);
    const int akg  = (lane >> 4) * 8;
    #pragma unroll
    for (int kt = 0; kt < 8; ++kt) {
      bf16x8 av = *(const bf16x8*)(&xs[cur][arow * RS + kt * 32 + akg]);
      #pragma unroll
      for (int jt = 0; jt < 4; ++jt)
        acc[jt] = __builtin_amdgcn_mfma_f32_16x16x32_bf16(av, bfrag[jt][kt], acc[jt], 0, 0, 0);
    }
    // score partial for this wave's 16 rows / 64 cols
    float sc[4] = {0.f, 0.f, 0.f, 0.f};
    #pragma unroll
    for (int jt = 0; jt < 4; ++jt) {
      #pragma unroll
      for (int r = 0; r < 4; ++r)
        sc[r] += fast_tanh(acc[jt][r]) * w2v[jt];
    }
    // reduce across the 16 cols held by the 16-lane group
    #pragma unroll
    for (int m = 1; m <= 8; m <<= 1) {
      #pragma unroll
      for (int r = 0; r < 4; ++r) sc[r] += __shfl_xor(sc[r], m, 64);
    }
    if ((lane & 15) == 0) {
      const int rbase = h * 16 + (lane >> 4) * 4;   // C/D: row=(lane>>4)*4+reg
      #pragma unroll
      for (int r = 0; r < 4; ++r) sp[jg][rbase + r] = sc[r];
    }
    __syncthreads();   // B1: scores visible (also drains prefetch loads)

    // ---- exp phase (no max subtraction: |s| <= ||w2||_1 <= 12.8) ----
    if (tid < PT) {
      float s = sp[0][tid] + sp[1][tid];
      float e = __builtin_amdgcn_exp2f(s * 1.4426950408889634f);
      expw[tid] = e;
      zacc += e;
    }
    __syncthreads();   // B2: expw visible

    // ---- pooling phase: pacc += exp(s_p) * x[p][e] ----
    #pragma unroll
    for (int pp = 0; pp < 32; ++pp) {
      const int p = pq * 32 + pp;
      pacc += expw[p] * bf2f(xs[cur][p * RS + pe]);
    }

    // ---- write next tile into the other buffer ----
    if (t + 1 < NT) {
      write_tile(cur ^ 1);
      __syncthreads(); // B3: next buffer ready before next MFMA phase
    }
  }

  // ---- epilogue: combine partials, normalize, store ----
  pool2[pq][pe] = pacc;
  if (tid < PT) zarr[tid] = zacc;
  __syncthreads();
  if (tid < NE) {
    float z = 0.f;
    #pragma unroll
    for (int i = 0; i < PT; ++i) z += zarr[i];
    float v = pool2[0][tid] + pool2[1][tid];
    out[(size_t)b * NE + tid] = v / z;
  }
}

extern "C" void kernel_launch(void* const* d_in, const int* in_sizes, int n_in,
                              void* d_out, int out_size, void* d_ws, size_t ws_size,
                              hipStream_t stream) {
  (void)in_sizes; (void)n_in; (void)out_size; (void)d_ws; (void)ws_size;
  const float* x  = (const float*)d_in[0];
  const float* w1 = (const float*)d_in[1];
  const float* w2 = (const float*)d_in[2];
  float* out = (float*)d_out;
  pathattn_kernel<<<NB, 512, 0, stream>>>(x, w1, w2, out);
}

// Round 2
// 45.842 us; speedup vs baseline: 1.0264x; 1.0264x over previous
//
#include <hip/hip_runtime.h>

#define NB 256
#define NP 512
#define NE 256
#define NH 128
#define PT 64              // pool-dim rows per tile
#define HALF 256           // pool rows handled per block (P split across 2 blocks)
#define NT (HALF / PT)     // 4 tiles per block
#define RS 264             // LDS row stride in shorts (256 + 8 pad)

typedef __attribute__((ext_vector_type(8))) short bf16x8;
typedef __attribute__((ext_vector_type(4))) short short4v;
typedef __attribute__((ext_vector_type(4))) float f32x4;

__device__ __forceinline__ short f2bf(float f) {
  union { float f; unsigned u; } v; v.f = f;
  unsigned r = v.u + 0x7fffu + ((v.u >> 16) & 1u);   // RNE
  return (short)(r >> 16);
}
__device__ __forceinline__ float bf2f(short s) {
  union { unsigned u; float f; } v;
  v.u = ((unsigned)(unsigned short)s) << 16;
  return v.f;
}
// tanh(x) = 1 - 2/(exp2(2*log2e*x)+1)
__device__ __forceinline__ float fast_tanh(float x) {
  float u = __builtin_amdgcn_exp2f(x * 2.8853900817779268f);
  return 1.0f - 2.0f * __builtin_amdgcn_rcpf(u + 1.0f);
}

// Each block: one (b, half-of-P). Produces unnormalized pooled partial + Z partial.
__global__ __launch_bounds__(512, 4) void pathattn_part(
    const float* __restrict__ x, const float* __restrict__ w1,
    const float* __restrict__ w2, float* __restrict__ wsPool,
    float* __restrict__ wsZ) {
  __shared__ short xs[2][PT * RS];     // bf16 x tiles, double-buffered (~66 KB)
  __shared__ float sp[8][PT];          // per-wave (j-tile) score partials
  __shared__ float expw[PT];           // exp(score) for current tile
  __shared__ float pool2[2][NE];       // pooled partials (2 p-halves)

  const int tid  = threadIdx.x;
  const int lane = tid & 63;
  const int wid  = tid >> 6;           // 0..7 — wave owns j-tile `wid`
  const int b    = blockIdx.x >> 1;
  const int half = blockIdx.x & 1;
  const float* xb = x + (size_t)b * NP * NE + (size_t)half * HALF * NE;

  // ---- per-wave w1 j-tile into registers as bf16 B-fragments (8 k-tiles) ----
  // B[k][n] = w1[j0+n][k]; lane holds n=lane&15, k = kt*32 + (lane>>4)*8 + i
  bf16x8 bfrag[8];
  float w2v;
  const int n15 = lane & 15;
  const int kg8 = (lane >> 4) * 8;
  {
    const int j = wid * 16 + n15;
    w2v = w2[j];
    #pragma unroll
    for (int kt = 0; kt < 8; ++kt) {
      const f32x4* s = (const f32x4*)(w1 + j * NE + kt * 32 + kg8);
      f32x4 a = s[0], c = s[1];
      bf16x8 v;
      v[0]=f2bf(a[0]); v[1]=f2bf(a[1]); v[2]=f2bf(a[2]); v[3]=f2bf(a[3]);
      v[4]=f2bf(c[0]); v[5]=f2bf(c[1]); v[6]=f2bf(c[2]); v[7]=f2bf(c[3]);
      bfrag[kt] = v;
    }
  }

  // ---- staging: global fp32 -> regs -> bf16 LDS (padded rows) ----
  f32x4 streg[8];
  auto issue_loads = [&](int tile) {
    const float* base = xb + tile * PT * NE;
    #pragma unroll
    for (int rr = 0; rr < 8; ++rr) {
      int f   = rr * 512 + tid;        // float4 index within tile
      int row = f >> 6;
      int c4  = f & 63;
      streg[rr] = *(const f32x4*)(base + row * NE + c4 * 4);
    }
  };
  auto write_tile = [&](int buf) {
    #pragma unroll
    for (int rr = 0; rr < 8; ++rr) {
      int f   = rr * 512 + tid;
      int row = f >> 6;
      int c4  = f & 63;
      short4v v;
      v[0]=f2bf(streg[rr][0]); v[1]=f2bf(streg[rr][1]);
      v[2]=f2bf(streg[rr][2]); v[3]=f2bf(streg[rr][3]);
      *(short4v*)(&xs[buf][row * RS + c4 * 4]) = v;
    }
  };

  issue_loads(0);
  write_tile(0);
  __syncthreads();

  float pacc = 0.f;                    // pooling accumulator (one e per thread)
  float zacc = 0.f;                    // Z accumulator (wave 0, tid<64)
  const int pe = tid & 255;
  const int pq = tid >> 8;             // 0..1: which 32-row half of the tile

  for (int t = 0; t < NT; ++t) {
    const int cur = t & 1;
    if (t + 1 < NT) issue_loads(t + 1);

    // ---- MFMA: this wave's 16 j-cols x all 64 rows of the tile ----
    f32x4 acc[4];
    #pragma unroll
    for (int rt = 0; rt < 4; ++rt) acc[rt] = (f32x4){0.f,0.f,0.f,0.f};
    #pragma unroll
    for (int kt = 0; kt < 8; ++kt) {
      #pragma unroll
      for (int rt = 0; rt < 4; ++rt) {
        bf16x8 av = *(const bf16x8*)(&xs[cur][(rt*16 + n15) * RS + kt*32 + kg8]);
        acc[rt] = __builtin_amdgcn_mfma_f32_16x16x32_bf16(av, bfrag[kt], acc[rt], 0, 0, 0);
      }
    }
    // tanh, weight by w2, reduce across this wave's 16 cols (lane&15 groups)
    float sc[4][4];
    #pragma unroll
    for (int rt = 0; rt < 4; ++rt)
      #pragma unroll
      for (int r = 0; r < 4; ++r)
        sc[rt][r] = fast_tanh(acc[rt][r]) * w2v;
    #pragma unroll
    for (int m = 1; m <= 8; m <<= 1)
      #pragma unroll
      for (int rt = 0; rt < 4; ++rt)
        #pragma unroll
        for (int r = 0; r < 4; ++r)
          sc[rt][r] += __shfl_xor(sc[rt][r], m, 64);
    if (n15 == 0) {
      #pragma unroll
      for (int rt = 0; rt < 4; ++rt) {
        const int rbase = rt * 16 + (lane >> 4) * 4;  // C/D: row=(lane>>4)*4+r
        #pragma unroll
        for (int r = 0; r < 4; ++r) sp[wid][rbase + r] = sc[rt][r];
      }
    }
    __syncthreads();   // B1: scores visible (drains prefetch loads too)

    // ---- exp (no max subtraction: |s| <= ||w2||_1 <= 12.8) ----
    if (tid < PT) {
      float s = 0.f;
      #pragma unroll
      for (int w = 0; w < 8; ++w) s += sp[w][tid];
      float e = __builtin_amdgcn_exp2f(s * 1.4426950408889634f);
      expw[tid] = e;
      zacc += e;
    }
    __syncthreads();   // B2: expw visible

    // ---- pooling: pacc += exp(s_p) * x[p][e] ----
    #pragma unroll
    for (int pp = 0; pp < 32; ++pp) {
      const int p = pq * 32 + pp;
      pacc += expw[p] * bf2f(xs[cur][p * RS + pe]);
    }

    if (t + 1 < NT) {
      write_tile(cur ^ 1);
      __syncthreads(); // B3: next buffer ready
    }
  }

  // ---- epilogue: write partials to workspace ----
  pool2[pq][pe] = pacc;
  float z = zacc;
  if (wid == 0) {
    #pragma unroll
    for (int m = 1; m <= 32; m <<= 1) z += __shfl_xor(z, m, 64);
  }
  __syncthreads();
  if (tid < NE)
    wsPool[(size_t)blockIdx.x * NE + tid] = pool2[0][tid] + pool2[1][tid];
  if (tid == 0)
    wsZ[blockIdx.x] = z;
}

// Combine the two P-halves and normalize.
__global__ void pathattn_combine(const float* __restrict__ wsPool,
                                 const float* __restrict__ wsZ,
                                 float* __restrict__ out) {
  const int b = blockIdx.x, e = threadIdx.x;
  float v = wsPool[(size_t)(2*b) * NE + e] + wsPool[(size_t)(2*b+1) * NE + e];
  float z = wsZ[2*b] + wsZ[2*b+1];
  out[(size_t)b * NE + e] = v / z;
}

extern "C" void kernel_launch(void* const* d_in, const int* in_sizes, int n_in,
                              void* d_out, int out_size, void* d_ws, size_t ws_size,
                              hipStream_t stream) {
  (void)in_sizes; (void)n_in; (void)out_size; (void)ws_size;
  const float* x  = (const float*)d_in[0];
  const float* w1 = (const float*)d_in[1];
  const float* w2 = (const float*)d_in[2];
  float* out = (float*)d_out;
  float* wsPool = (float*)d_ws;                 // [512][256]
  float* wsZ    = wsPool + 512 * NE;            // [512]
  pathattn_part<<<2 * NB, 512, 0, stream>>>(x, w1, w2, wsPool, wsZ);
  pathattn_combine<<<NB, NE, 0, stream>>>(wsPool, wsZ, out);
}

// Round 3
// 39.108 us; speedup vs baseline: 1.2031x; 1.1722x over previous
//
#include <hip/hip_runtime.h>

#define NB 256
#define NP 512
#define NE 256
#define NH 128
#define PT 64              // pool-dim rows per tile
#define HALF 256           // pool rows per block (P split across 2 blocks)
#define NT (HALF / PT)     // 4 tiles per block
#define RS 264             // LDS row stride in shorts (256 + 8 pad)
#define SP_LD 68           // sp row stride (floats)

typedef __attribute__((ext_vector_type(8))) short bf16x8;
typedef __attribute__((ext_vector_type(4))) short short4v;
typedef __attribute__((ext_vector_type(4))) float f32x4;

__device__ __forceinline__ short f2bf(float f) {
  union { float f; unsigned u; } v; v.f = f;
  unsigned r = v.u + 0x7fffu + ((v.u >> 16) & 1u);   // RNE
  return (short)(r >> 16);
}
__device__ __forceinline__ float bf2f(short s) {
  union { unsigned u; float f; } v;
  v.u = ((unsigned)(unsigned short)s) << 16;
  return v.f;
}
// tanh(x) = 1 - 2/(exp2(2*log2e*x)+1)
__device__ __forceinline__ float fast_tanh(float x) {
  float u = __builtin_amdgcn_exp2f(x * 2.8853900817779268f);
  return 1.0f - 2.0f * __builtin_amdgcn_rcpf(u + 1.0f);
}

union SMem {
  struct {
    short xs[2][PT * RS];      // bf16 x tiles, double-buffered (66 KB)
    float sp[8][SP_LD];        // per-wave score partials
  } s;
  float pool[16][NE];          // epilogue pooled partials (aliases xs[0])
};

// Each block: one (b, half-of-P). Produces unnormalized pooled partial + Z partial.
__global__ __launch_bounds__(512, 4) void pathattn_part(
    const float* __restrict__ x, const float* __restrict__ w1,
    const float* __restrict__ w2, float* __restrict__ wsPool,
    float* __restrict__ wsZ) {
  __shared__ SMem sm;

  const int tid  = threadIdx.x;
  const int lane = tid & 63;
  const int wid  = tid >> 6;           // 0..7 — wave owns h-tile `wid` (16 h)
  const int n15  = lane & 15;
  const int l4   = lane >> 4;          // 0..3
  const int kg8  = l4 * 8;
  const int b    = blockIdx.x >> 1;
  const int half = blockIdx.x & 1;
  const float* xb = x + (size_t)b * NP * NE + (size_t)half * HALF * NE;

  // ---- A-fragments: w1 rows h = wid*16 + n15, k contiguous (8 k-tiles) ----
  // A[row][k]: lane holds row=lane&15, k = kt*32 + (lane>>4)*8 + i
  bf16x8 afrag[8];
  float w2v[4];
  {
    const int h = wid * 16 + n15;
    #pragma unroll
    for (int kt = 0; kt < 8; ++kt) {
      const f32x4* s = (const f32x4*)(w1 + h * NE + kt * 32 + kg8);
      f32x4 a = s[0], c = s[1];
      bf16x8 v;
      v[0]=f2bf(a[0]); v[1]=f2bf(a[1]); v[2]=f2bf(a[2]); v[3]=f2bf(a[3]);
      v[4]=f2bf(c[0]); v[5]=f2bf(c[1]); v[6]=f2bf(c[2]); v[7]=f2bf(c[3]);
      afrag[kt] = v;
    }
    #pragma unroll
    for (int r = 0; r < 4; ++r) w2v[r] = w2[wid * 16 + l4 * 4 + r];
  }

  // ---- staging: global fp32 -> regs -> bf16 LDS (padded rows) ----
  f32x4 streg[8];
  auto issue_loads = [&](int tile) {
    const float* base = xb + tile * PT * NE;
    #pragma unroll
    for (int rr = 0; rr < 8; ++rr) {
      int f   = rr * 512 + tid;        // float4 index within tile
      int row = f >> 6;
      int c4  = f & 63;
      streg[rr] = *(const f32x4*)(base + row * NE + c4 * 4);
    }
  };
  auto write_tile = [&](int buf) {
    #pragma unroll
    for (int rr = 0; rr < 8; ++rr) {
      int f   = rr * 512 + tid;
      int row = f >> 6;
      int c4  = f & 63;
      short4v v;
      v[0]=f2bf(streg[rr][0]); v[1]=f2bf(streg[rr][1]);
      v[2]=f2bf(streg[rr][2]); v[3]=f2bf(streg[rr][3]);
      *(short4v*)(&sm.s.xs[buf][row * RS + c4 * 4]) = v;
    }
  };

  issue_loads(0);
  write_tile(0);
  __syncthreads();

  // pooling ownership: thread owns 8 e's (chunk) x 4 rows (rowg*4+it)
  const int rowg  = tid >> 5;          // 0..15
  const int chunk = tid & 31;          // e-chunk: e = chunk*8 .. +7
  f32x4 pacc0 = {0.f,0.f,0.f,0.f}, pacc1 = {0.f,0.f,0.f,0.f};
  float zacc = 0.f;

  for (int t = 0; t < NT; ++t) {
    const int cur = t & 1;
    if (t + 1 < NT) issue_loads(t + 1);   // in flight across MFMA + B1 + pooling

    // ---- MFMA: D[h][p] = sum_k w1[h][k] * x[p][k]  (swapped operands) ----
    const short* xcur = sm.s.xs[cur];
    f32x4 acc[4];
    #pragma unroll
    for (int pt = 0; pt < 4; ++pt) acc[pt] = (f32x4){0.f,0.f,0.f,0.f};
    #pragma unroll
    for (int kt = 0; kt < 8; ++kt) {
      #pragma unroll
      for (int pt = 0; pt < 4; ++pt) {
        // B[k][p]: lane holds col p = pt*16 + n15, k = kt*32 + kg8 + i
        bf16x8 bv = *(const bf16x8*)(&xcur[(pt * 16 + n15) * RS + kt * 32 + kg8]);
        acc[pt] = __builtin_amdgcn_mfma_f32_16x16x32_bf16(afrag[kt], bv, acc[pt], 0, 0, 0);
      }
    }
    // D layout: col(p) = lane&15, row(h) = wid*16 + (lane>>4)*4 + reg.
    // Score partial for p: sum_r tanh(acc)*w2 locally, then 2 shuffles across l4.
    #pragma unroll
    for (int pt = 0; pt < 4; ++pt) {
      float s = 0.f;
      #pragma unroll
      for (int r = 0; r < 4; ++r) s += fast_tanh(acc[pt][r]) * w2v[r];
      s += __shfl_xor(s, 16, 64);
      s += __shfl_xor(s, 32, 64);
      if (l4 == 0) sm.s.sp[wid][pt * 16 + n15] = s;
    }
    __syncthreads();   // B1: scores visible (drains prefetch loads too)

    // ---- exp: every wave computes expw[p] for p = lane (redundant, no barrier) ----
    float ssum = 0.f;
    #pragma unroll
    for (int w = 0; w < 8; ++w) ssum += sm.s.sp[w][lane];
    float e = __builtin_amdgcn_exp2f(ssum * 1.4426950408889634f);
    zacc += e;   // per-lane Z partial (identical in every wave; wave 0 used at end)

    // ---- pooling: thread's 4 rows x 8 e's, b128 LDS reads ----
    #pragma unroll
    for (int it = 0; it < 4; ++it) {
      const int p   = rowg * 4 + it;
      const int src = wid * 8 + (lane >> 5) * 4 + it;   // lane holding expw[p]
      float ep = __shfl(e, src, 64);
      bf16x8 v = *(const bf16x8*)(&xcur[p * RS + chunk * 8]);
      pacc0[0] += ep * bf2f(v[0]);
      pacc0[1] += ep * bf2f(v[1]);
      pacc0[2] += ep * bf2f(v[2]);
      pacc0[3] += ep * bf2f(v[3]);
      pacc1[0] += ep * bf2f(v[4]);
      pacc1[1] += ep * bf2f(v[5]);
      pacc1[2] += ep * bf2f(v[6]);
      pacc1[3] += ep * bf2f(v[7]);
    }

    if (t + 1 < NT) write_tile(cur ^ 1);
    __syncthreads();   // B2: next buffer ready / xs reads done
  }

  // ---- epilogue: reduce pooled partials across the 16 row-groups ----
  // pool[][] aliases xs; all xs reads completed before last B2.
  *(f32x4*)(&sm.pool[rowg][chunk * 8])     = pacc0;
  *(f32x4*)(&sm.pool[rowg][chunk * 8 + 4]) = pacc1;
  __syncthreads();
  if (tid < NE) {
    float v = 0.f;
    #pragma unroll
    for (int rg = 0; rg < 16; ++rg) v += sm.pool[rg][tid];
    wsPool[(size_t)blockIdx.x * NE + tid] = v;
  }
  if (wid == 0) {
    float z = zacc;
    #pragma unroll
    for (int m = 1; m <= 32; m <<= 1) z += __shfl_xor(z, m, 64);
    if (lane == 0) wsZ[blockIdx.x] = z;
  }
}

// Combine the two P-halves and normalize.
__global__ void pathattn_combine(const float* __restrict__ wsPool,
                                 const float* __restrict__ wsZ,
                                 float* __restrict__ out) {
  const int b = blockIdx.x, e = threadIdx.x;
  float v = wsPool[(size_t)(2*b) * NE + e] + wsPool[(size_t)(2*b+1) * NE + e];
  float z = wsZ[2*b] + wsZ[2*b+1];
  out[(size_t)b * NE + e] = v / z;
}

extern "C" void kernel_launch(void* const* d_in, const int* in_sizes, int n_in,
                              void* d_out, int out_size, void* d_ws, size_t ws_size,
                              hipStream_t stream) {
  (void)in_sizes; (void)n_in; (void)out_size; (void)ws_size;
  const float* x  = (const float*)d_in[0];
  const float* w1 = (const float*)d_in[1];
  const float* w2 = (const float*)d_in[2];
  float* out = (float*)d_out;
  float* wsPool = (float*)d_ws;                 // [512][256]
  float* wsZ    = wsPool + 512 * NE;            // [512]
  pathattn_part<<<2 * NB, 512, 0, stream>>>(x, w1, w2, wsPool, wsZ);
  pathattn_combine<<<NB, NE, 0, stream>>>(wsPool, wsZ, out);
}